// Round 6
// baseline (139.875 us; speedup 1.0000x reference)
//
#include <hip/hip_runtime.h>

#define NV 13824   // 24*24*24 voxels per batch
#define CCH 64     // channels
#define NB 2       // batch

// ---------------------------------------------------------------------------
// Kernel 1 (v5): q/k/v register-tiled GEMM, A read straight from global.
// Global x is [c][n] == the GEMM's [k][row] layout, so no LDS staging for A:
// lanes 0-15 (row-groups) read 256B contiguous per k, 4x colg duplication is
// dedup'd by the coalescer/L1. W^T (48KB) in LDS; b-reads are 16-lane
// broadcasts (4 distinct addrs/wave, conflict-free). M=64 -> 432 blocks,
// 3 blocks/CU (LDS-limited), ~3 waves/SIMD.
// Thread tile: 4 rows x 4 cols x 3 tensors (48 FMA per 3 ds_read_b128 + 1 VMEM).
// q epilogue pre-scaled by hd^-0.5 = 0.25 (attn then skips it).
// Stores: wave-instr = 16 rows x 64B contiguous -> full 32B sectors.
// XCD chunk swizzle: 432 = 8*54; XCD x produces row chunk [x*3456, (x+1)*3456).
// ---------------------------------------------------------------------------
__global__ __launch_bounds__(256) void qkv_kernel(
    const float* __restrict__ x,
    const float* __restrict__ Wq, const float* __restrict__ bq,
    const float* __restrict__ Wk, const float* __restrict__ bk,
    const float* __restrict__ Wv, const float* __restrict__ bv,
    float* __restrict__ qo, float* __restrict__ ko, float* __restrict__ vo)
{
    __shared__ float sWT[3 * 64 * 64];   // [m][k][o], 48KB
    __shared__ float sB[3 * 64];

    const int t   = threadIdx.x;
    const int bid = blockIdx.x;
    const int lb  = (bid & 7) * 54 + (bid >> 3);   // bijective XCD chunking

    // stage W transposed: lane o = t&63, k-chunk = t>>6; float4 global loads,
    // scalar ds_writes at consecutive-per-lane addresses (conflict-free)
    {
        const int o  = t & 63;
        const int kk = t >> 6;                      // 0..3 (16 k each)
        const float* const Ws[3] = {Wq, Wk, Wv};
        #pragma unroll
        for (int m = 0; m < 3; ++m) {
            const float* wm = Ws[m] + o * 64 + kk * 16;
            float* dd = sWT + m * 4096 + o;
            #pragma unroll
            for (int k4 = 0; k4 < 4; ++k4) {
                const float4 wv4 = *(const float4*)(wm + k4 * 4);
                dd[(kk * 16 + k4 * 4 + 0) * 64] = wv4.x;
                dd[(kk * 16 + k4 * 4 + 1) * 64] = wv4.y;
                dd[(kk * 16 + k4 * 4 + 2) * 64] = wv4.z;
                dd[(kk * 16 + k4 * 4 + 3) * 64] = wv4.w;
            }
        }
        if (t < 64) {
            sB[t]       = bq[t] * 0.25f;   // q-scale folded into bias
            sB[64 + t]  = bk[t];
            sB[128 + t] = bv[t];
        }
    }
    __syncthreads();

    const int n0 = lb * 64;               // 64 | NV -> no batch straddle
    const int b  = n0 / NV;
    const int nn = n0 - b * NV;
    const int r0 = (t & 15) * 4;          // row base within tile
    const int c0 = (t >> 4) * 4;          // col base (wave has 4 colg -> bcast)

    const float* xb = x + (size_t)b * CCH * NV + nn + r0;

    float4 acc[3][4];                     // [m][col] over 4 rows (x..w)
    #pragma unroll
    for (int m = 0; m < 3; ++m)
        #pragma unroll
        for (int c = 0; c < 4; ++c)
            acc[m][c] = make_float4(0.f, 0.f, 0.f, 0.f);

    #pragma unroll 8
    for (int k = 0; k < 64; ++k) {
        const float4 a = *(const float4*)(xb + (size_t)k * NV);
        #pragma unroll
        for (int m = 0; m < 3; ++m) {
            const float4 bb = *(const float4*)(sWT + m * 4096 + k * 64 + c0);
#define QKV_C(CI, S) { acc[m][CI].x += a.x*(S); acc[m][CI].y += a.y*(S); \
                       acc[m][CI].z += a.z*(S); acc[m][CI].w += a.w*(S); }
            QKV_C(0, bb.x) QKV_C(1, bb.y) QKV_C(2, bb.z) QKV_C(3, bb.w)
#undef QKV_C
        }
    }

    // epilogue: per m, per row rr: float4 over cols c0..c0+3
    float* const outs[3] = {qo, ko, vo};
    #pragma unroll
    for (int m = 0; m < 3; ++m) {
        const float4 bb = *(const float4*)(sB + m * 64 + c0);
        const float  sc = (m == 0) ? 0.25f : 1.0f;
        float* ob = outs[m] + (size_t)(n0 + r0) * 64 + c0;
#define QKV_ROW(RR, F) { \
        const float4 o4 = make_float4(acc[m][0].F * sc + bb.x, \
                                      acc[m][1].F * sc + bb.y, \
                                      acc[m][2].F * sc + bb.z, \
                                      acc[m][3].F * sc + bb.w); \
        *(float4*)(ob + (size_t)(RR) * 64) = o4; }
        QKV_ROW(0, x) QKV_ROW(1, y) QKV_ROW(2, z) QKV_ROW(3, w)
#undef QKV_ROW
    }
}

// ---------------------------------------------------------------------------
// Kernel 2 (v3): local attention. Lane map vb = t&31, hh = t>>5
// (coff = hh*8): 32 consecutive voxels per half-wave -> out/x accesses are
// dense 128B lines (v2's map scattered 4B over 64 sectors per instr).
// Partner for the 8+8 dim-split dot is t^32 (same wave). q pre-scaled by qkv.
// No max-subtraction (logits sigma~1, exp safe in fp32; math identical).
// OOB neighbors: logit 0 participates in softmax (zero-padded k), v = 0.
// XCD chunk swizzle: 864 = 8*108, aligned with qkv's chunks.
// ---------------------------------------------------------------------------
__global__ __launch_bounds__(256) void attn_kernel(
    const float* __restrict__ x,
    const float* __restrict__ qw,
    const float* __restrict__ kw,
    const float* __restrict__ vw,
    float* __restrict__ out)
{
    const int t    = threadIdx.x;
    const int bid  = blockIdx.x;
    const int lb   = (bid & 7) * 108 + (bid >> 3);   // bijective XCD chunking
    const int vb   = t & 31;
    const int hh   = t >> 5;             // 0..7; coff = head*16+half*8 = hh*8
    const int coff = hh * 8;
    const int gr   = lb * 32 + vb;
    const int b    = gr / NV;
    const int n    = gr - b * NV;
    const int d    = n / 576;
    const int rem  = n - d * 576;
    const int r    = rem / 24;
    const int w    = rem - r * 24;

    // neighbor element indices (-1 if out of bounds), torch-unfold order
    int nidx[27];
    #pragma unroll
    for (int i3 = 0; i3 < 3; ++i3)
    #pragma unroll
    for (int j3 = 0; j3 < 3; ++j3)
    #pragma unroll
    for (int l3 = 0; l3 < 3; ++l3) {
        const int dd = d + i3 - 1;
        const int rr = r + j3 - 1;
        const int ww = w + l3 - 1;
        const bool ok = ((unsigned)dd < 24u) & ((unsigned)rr < 24u) & ((unsigned)ww < 24u);
        nidx[(i3 * 3 + j3) * 3 + l3] = ok ? ((dd * 24 + rr) * 24 + ww) : -1;
    }

    // q fragment (8 floats, already scaled by 0.25 in qkv)
    const float4* qp = (const float4*)(qw + (size_t)gr * 64 + coff);
    const float4 q0 = qp[0], q1 = qp[1];

    const float* kbase = kw + (size_t)b * NV * 64 + coff;

    float logit[27];
    #pragma unroll
    for (int j = 0; j < 27; ++j) {
        float a = 0.f;
        if (nidx[j] >= 0) {
            const float4* kp = (const float4*)(kbase + (size_t)nidx[j] * 64);
            const float4 k0 = kp[0], k1 = kp[1];
            a  = q0.x * k0.x + q0.y * k0.y + q0.z * k0.z + q0.w * k0.w;
            a += q1.x * k1.x + q1.y * k1.y + q1.z * k1.z + q1.w * k1.w;
        }
        a += __shfl_xor(a, 32, 64);   // combine the two 8-dim halves
        logit[j] = a;                  // OOB -> 0, still in softmax
    }

    float ssum = 0.f;
    #pragma unroll
    for (int j = 0; j < 27; ++j) {
        const float e = __expf(logit[j]);   // no max-subtract needed
        logit[j] = e;
        ssum += e;
    }
    const float inv = 1.f / ssum;

    float a0=0.f,a1=0.f,a2=0.f,a3=0.f,a4=0.f,a5=0.f,a6=0.f,a7=0.f;
    const float* vbase = vw + (size_t)b * NV * 64 + coff;
    #pragma unroll
    for (int j = 0; j < 27; ++j) {
        if (nidx[j] >= 0) {
            const float p = logit[j];
            const float4* vp = (const float4*)(vbase + (size_t)nidx[j] * 64);
            const float4 v0 = vp[0], v1 = vp[1];
            a0 += p * v0.x; a1 += p * v0.y; a2 += p * v0.z; a3 += p * v0.w;
            a4 += p * v1.x; a5 += p * v1.y; a6 += p * v1.z; a7 += p * v1.w;
        }
    }

    // residual add + channel-major store: lanes = 32 consecutive n -> each
    // access is a dense 128B line
    const size_t cb = (size_t)b * CCH * NV + (size_t)coff * NV + n;
    const float* xb = x + cb;
    float* ob = out + cb;
    float av[8] = {a0,a1,a2,a3,a4,a5,a6,a7};
    #pragma unroll
    for (int i = 0; i < 8; ++i) {
        ob[(size_t)i * NV] = xb[(size_t)i * NV] + av[i] * inv;
    }
}

// ---------------------------------------------------------------------------
extern "C" void kernel_launch(void* const* d_in, const int* in_sizes, int n_in,
                              void* d_out, int out_size, void* d_ws, size_t ws_size,
                              hipStream_t stream) {
    const float* x  = (const float*)d_in[0];
    // d_in[1] = cemb, unused by the reference forward
    const float* Wq = (const float*)d_in[2];
    const float* bq = (const float*)d_in[3];
    const float* Wk = (const float*)d_in[4];
    const float* bk = (const float*)d_in[5];
    const float* Wv = (const float*)d_in[6];
    const float* bv = (const float*)d_in[7];
    float* out = (float*)d_out;

    float* ws = (float*)d_ws;
    const size_t RC = (size_t)NB * NV * CCH;   // 1,769,472 floats per tensor
    float* q = ws;
    float* k = ws + RC;
    float* v = ws + 2 * RC;

    const int nrows = NB * NV;                  // 27648

    qkv_kernel<<<nrows / 64, 256, 0, stream>>>(x, Wq, bq, Wk, bk, Wv, bv, q, k, v);
    attn_kernel<<<nrows / 32, 256, 0, stream>>>(x, q, k, v, out);
}

// Round 8
// 107.841 us; speedup vs baseline: 1.2970x; 1.2970x over previous
//
#include <hip/hip_runtime.h>

#define NV 13824   // 24*24*24 voxels per batch
#define CCH 64     // channels
#define NB 2       // batch

// ---------------------------------------------------------------------------
// Kernel 1 (v5, unchanged): q/k/v register-tiled GEMM, A read from global.
// ---------------------------------------------------------------------------
__global__ __launch_bounds__(256) void qkv_kernel(
    const float* __restrict__ x,
    const float* __restrict__ Wq, const float* __restrict__ bq,
    const float* __restrict__ Wk, const float* __restrict__ bk,
    const float* __restrict__ Wv, const float* __restrict__ bv,
    float* __restrict__ qo, float* __restrict__ ko, float* __restrict__ vo)
{
    __shared__ float sWT[3 * 64 * 64];   // [m][k][o], 48KB
    __shared__ float sB[3 * 64];

    const int t   = threadIdx.x;
    const int bid = blockIdx.x;
    const int lb  = (bid & 7) * 54 + (bid >> 3);   // bijective XCD chunking

    {
        const int o  = t & 63;
        const int kk = t >> 6;                      // 0..3 (16 k each)
        const float* const Ws[3] = {Wq, Wk, Wv};
        #pragma unroll
        for (int m = 0; m < 3; ++m) {
            const float* wm = Ws[m] + o * 64 + kk * 16;
            float* dd = sWT + m * 4096 + o;
            #pragma unroll
            for (int k4 = 0; k4 < 4; ++k4) {
                const float4 wv4 = *(const float4*)(wm + k4 * 4);
                dd[(kk * 16 + k4 * 4 + 0) * 64] = wv4.x;
                dd[(kk * 16 + k4 * 4 + 1) * 64] = wv4.y;
                dd[(kk * 16 + k4 * 4 + 2) * 64] = wv4.z;
                dd[(kk * 16 + k4 * 4 + 3) * 64] = wv4.w;
            }
        }
        if (t < 64) {
            sB[t]       = bq[t] * 0.25f;   // q-scale folded into bias
            sB[64 + t]  = bk[t];
            sB[128 + t] = bv[t];
        }
    }
    __syncthreads();

    const int n0 = lb * 64;               // 64 | NV -> no batch straddle
    const int b  = n0 / NV;
    const int nn = n0 - b * NV;
    const int r0 = (t & 15) * 4;          // row base within tile
    const int c0 = (t >> 4) * 4;          // col base (wave has 4 colg -> bcast)

    const float* xb = x + (size_t)b * CCH * NV + nn + r0;

    float4 acc[3][4];                     // [m][col] over 4 rows (x..w)
    #pragma unroll
    for (int m = 0; m < 3; ++m)
        #pragma unroll
        for (int c = 0; c < 4; ++c)
            acc[m][c] = make_float4(0.f, 0.f, 0.f, 0.f);

    #pragma unroll 8
    for (int k = 0; k < 64; ++k) {
        const float4 a = *(const float4*)(xb + (size_t)k * NV);
        #pragma unroll
        for (int m = 0; m < 3; ++m) {
            const float4 bb = *(const float4*)(sWT + m * 4096 + k * 64 + c0);
#define QKV_C(CI, S) { acc[m][CI].x += a.x*(S); acc[m][CI].y += a.y*(S); \
                       acc[m][CI].z += a.z*(S); acc[m][CI].w += a.w*(S); }
            QKV_C(0, bb.x) QKV_C(1, bb.y) QKV_C(2, bb.z) QKV_C(3, bb.w)
#undef QKV_C
        }
    }

    float* const outs[3] = {qo, ko, vo};
    #pragma unroll
    for (int m = 0; m < 3; ++m) {
        const float4 bb = *(const float4*)(sB + m * 64 + c0);
        const float  sc = (m == 0) ? 0.25f : 1.0f;
        float* ob = outs[m] + (size_t)(n0 + r0) * 64 + c0;
#define QKV_ROW(RR, F) { \
        const float4 o4 = make_float4(acc[m][0].F * sc + bb.x, \
                                      acc[m][1].F * sc + bb.y, \
                                      acc[m][2].F * sc + bb.z, \
                                      acc[m][3].F * sc + bb.w); \
        *(float4*)(ob + (size_t)(RR) * 64) = o4; }
        QKV_ROW(0, x) QKV_ROW(1, y) QKV_ROW(2, z) QKV_ROW(3, w)
#undef QKV_ROW
    }
}

// ---------------------------------------------------------------------------
// Kernel 2 (v4): local attention.
// Gather map: 8 lanes = one voxel's full 256B k/v row (half=t&1, head=(t>>1)&3,
// vb=t>>3) -> coalesced 2KB/wave gathers. Taps are BRANCH-FREE: OOB index
// clamped to own row, contribution multiplied by 0/1 mask (preserves
// zero-padded-k semantics: OOB logit 0 enters softmax, v masked to 0).
// Unconditional unrolled loads -> deep ILP, no exec-mask serialization.
// Dense I/O: out/x go through padded LDS transpose so[32][65]; store phase
// uses 32-consecutive-voxel lanes -> every global access a 128B line.
// ---------------------------------------------------------------------------
__global__ __launch_bounds__(256) void attn_kernel(
    const float* __restrict__ x,
    const float* __restrict__ qw,
    const float* __restrict__ kw,
    const float* __restrict__ vw,
    float* __restrict__ out)
{
    __shared__ float so[32][65];   // padded: bank = (v + c) % 32, conflict-free

    const int t    = threadIdx.x;
    const int bid  = blockIdx.x;
    const int lb   = (bid & 7) * 108 + (bid >> 3);   // bijective XCD chunking
    const int half = t & 1;
    const int head = (t >> 1) & 3;
    const int vb   = t >> 3;             // 0..31
    const int n0g  = lb * 32;            // 32 | NV -> no batch straddle
    const int gr   = n0g + vb;
    const int b    = gr / NV;
    const int n    = gr - b * NV;
    const int d    = n / 576;
    const int rem  = n - d * 576;
    const int r    = rem / 24;
    const int w    = rem - r * 24;
    const int coff = head * 16 + half * 8;

    // branch-free neighbor table: clamped index + 0/1 mask
    int   idx[27];
    float msk[27];
    #pragma unroll
    for (int i3 = 0; i3 < 3; ++i3)
    #pragma unroll
    for (int j3 = 0; j3 < 3; ++j3)
    #pragma unroll
    for (int l3 = 0; l3 < 3; ++l3) {
        const int dd = d + i3 - 1;
        const int rr = r + j3 - 1;
        const int ww = w + l3 - 1;
        const bool ok = ((unsigned)dd < 24u) & ((unsigned)rr < 24u) & ((unsigned)ww < 24u);
        const int jj = (i3 * 3 + j3) * 3 + l3;
        idx[jj] = ok ? ((dd * 24 + rr) * 24 + ww) : n;
        msk[jj] = ok ? 1.f : 0.f;
    }

    // q fragment (8 floats, already scaled by 0.25 in qkv)
    const float4* qp = (const float4*)(qw + (size_t)gr * 64 + coff);
    const float4 q0 = qp[0], q1 = qp[1];

    const float* kbase = kw + (size_t)b * NV * 64 + coff;

    // unconditional masked dot per tap
    float logit[27];
    #pragma unroll
    for (int j = 0; j < 27; ++j) {
        const float4* kp = (const float4*)(kbase + (size_t)idx[j] * 64);
        const float4 k0 = kp[0], k1 = kp[1];
        float a;
        a  = q0.x * k0.x + q0.y * k0.y + q0.z * k0.z + q0.w * k0.w;
        a += q1.x * k1.x + q1.y * k1.y + q1.z * k1.z + q1.w * k1.w;
        logit[j] = a * msk[j];
    }
    #pragma unroll
    for (int j = 0; j < 27; ++j)
        logit[j] += __shfl_xor(logit[j], 1, 64);   // combine 8+8 dim halves

    float ssum = 0.f;
    #pragma unroll
    for (int j = 0; j < 27; ++j) {
        const float e = __expf(logit[j]);   // OOB: exp(0)=1 participates
        logit[j] = e;
        ssum += e;
    }
    const float inv = 1.f / ssum;

    float a0=0.f,a1=0.f,a2=0.f,a3=0.f,a4=0.f,a5=0.f,a6=0.f,a7=0.f;
    const float* vbase = vw + (size_t)b * NV * 64 + coff;
    #pragma unroll
    for (int j = 0; j < 27; ++j) {
        const float p = logit[j] * msk[j];   // OOB contributes v = 0
        const float4* vp = (const float4*)(vbase + (size_t)idx[j] * 64);
        const float4 v0 = vp[0], v1 = vp[1];
        a0 += p * v0.x; a1 += p * v0.y; a2 += p * v0.z; a3 += p * v0.w;
        a4 += p * v1.x; a5 += p * v1.y; a6 += p * v1.z; a7 += p * v1.w;
    }

    // LDS transpose: each lane deposits its 8 channels (scaled by inv)
    so[vb][coff + 0] = a0 * inv;  so[vb][coff + 1] = a1 * inv;
    so[vb][coff + 2] = a2 * inv;  so[vb][coff + 3] = a3 * inv;
    so[vb][coff + 4] = a4 * inv;  so[vb][coff + 5] = a5 * inv;
    so[vb][coff + 6] = a6 * inv;  so[vb][coff + 7] = a7 * inv;
    __syncthreads();

    // dense store phase: lanes = 32 consecutive voxels, 8 channels each
    const int vv = t & 31;
    const int cg = t >> 5;
    const int bs = n0g / NV;
    const int nb0 = n0g - bs * NV;
    const float* xb = x   + (size_t)bs * CCH * NV + nb0 + vv;
    float*       ob = out + (size_t)bs * CCH * NV + nb0 + vv;
    #pragma unroll
    for (int i = 0; i < 8; ++i) {
        const int c = cg * 8 + i;
        ob[(size_t)c * NV] = xb[(size_t)c * NV] + so[vv][c];
    }
}

// ---------------------------------------------------------------------------
extern "C" void kernel_launch(void* const* d_in, const int* in_sizes, int n_in,
                              void* d_out, int out_size, void* d_ws, size_t ws_size,
                              hipStream_t stream) {
    const float* x  = (const float*)d_in[0];
    // d_in[1] = cemb, unused by the reference forward
    const float* Wq = (const float*)d_in[2];
    const float* bq = (const float*)d_in[3];
    const float* Wk = (const float*)d_in[4];
    const float* bk = (const float*)d_in[5];
    const float* Wv = (const float*)d_in[6];
    const float* bv = (const float*)d_in[7];
    float* out = (float*)d_out;

    float* ws = (float*)d_ws;
    const size_t RC = (size_t)NB * NV * CCH;   // 1,769,472 floats per tensor
    float* q = ws;
    float* k = ws + RC;
    float* v = ws + 2 * RC;

    const int nrows = NB * NV;                  // 27648

    qkv_kernel<<<nrows / 64, 256, 0, stream>>>(x, Wq, bq, Wk, bk, Wv, bv, q, k, v);
    attn_kernel<<<nrows / 32, 256, 0, stream>>>(x, q, k, v, out);
}